// Round 5
// baseline (98092.072 us; speedup 1.0000x reference)
//
#include <hip/hip_runtime.h>
#include <cstdint>
#include <cstddef>

typedef unsigned long long u64;
typedef unsigned int u32;

#define NROWS 8192
#define DIN   1024
#define DOUT  4096
#define GAMMA 0.01618f

// monotone order-preserving fp32 -> u32 (ascending); s>0 <=> key > 0x80000000
__device__ __forceinline__ u32 mono_key(float f) {
    u32 u = __float_as_uint(f);
    return (u & 0x80000000u) ? ~u : (u | 0x80000000u);
}

// 64-lane max of a u64 via two 32-bit shuffles per step
__device__ __forceinline__ u64 wave_max64(u64 x) {
#pragma unroll
    for (int off = 32; off >= 1; off >>= 1) {
        u32 lo = (u32)x, hi = (u32)(x >> 32);
        u32 olo = __shfl_xor(lo, off, 64);
        u32 ohi = __shfl_xor(hi, off, 64);
        u64 o = ((u64)ohi << 32) | olo;
        if (o > x) x = o;
    }
    return x;
}

// ---------------------------------------------------------------------------
// K1: H = leaky_relu(X @ W^T + b), f32 inputs, f64 ACCUMULATION (each product
// exact in f64, single final rounding -> matches an f64 np reference exactly
// and sits inside the noise ball of any f32-order reference).
// 128x128 tile, BK=16, 256 threads, 8x8 per thread.
// ---------------------------------------------------------------------------
__global__ __launch_bounds__(256)
void gemm_lrelu_f64acc(const float* __restrict__ X, const float* __restrict__ Wt,
                       const float* __restrict__ bias, float* __restrict__ H) {
    __shared__ float As[16][128];
    __shared__ float Bs[16][128];
    const int bx = blockIdx.x;          // n-tile 0..31
    const int by = blockIdx.y;          // m-tile 0..63
    const int tid = threadIdx.x;
    const int tx = tid & 15, ty = tid >> 4;
    const int m0 = by * 128, n0 = bx * 128;

    double acc[8][8];
#pragma unroll
    for (int i = 0; i < 8; i++)
#pragma unroll
        for (int j = 0; j < 8; j++) acc[i][j] = 0.0;

    for (int k0 = 0; k0 < DIN; k0 += 16) {
#pragma unroll
        for (int h = 0; h < 2; h++) {
            int id = tid + h * 256;
            int r  = id >> 2;
            int kc = id & 3;
            float4 a = *(const float4*)(X  + (size_t)(m0 + r) * DIN + k0 + kc * 4);
            As[kc * 4 + 0][r] = a.x; As[kc * 4 + 1][r] = a.y;
            As[kc * 4 + 2][r] = a.z; As[kc * 4 + 3][r] = a.w;
            float4 b = *(const float4*)(Wt + (size_t)(n0 + r) * DIN + k0 + kc * 4);
            Bs[kc * 4 + 0][r] = b.x; Bs[kc * 4 + 1][r] = b.y;
            Bs[kc * 4 + 2][r] = b.z; Bs[kc * 4 + 3][r] = b.w;
        }
        __syncthreads();
#pragma unroll
        for (int kk = 0; kk < 16; kk++) {
            float a[8], b[8];
            *(float4*)&a[0] = *(const float4*)&As[kk][ty * 4];
            *(float4*)&a[4] = *(const float4*)&As[kk][64 + ty * 4];
            *(float4*)&b[0] = *(const float4*)&Bs[kk][tx * 4];
            *(float4*)&b[4] = *(const float4*)&Bs[kk][64 + tx * 4];
#pragma unroll
            for (int i = 0; i < 8; i++)
#pragma unroll
                for (int j = 0; j < 8; j++)
                    acc[i][j] += (double)a[i] * (double)b[j];
        }
        __syncthreads();
    }

#pragma unroll
    for (int i = 0; i < 8; i++) {
        int mm = m0 + ((i < 4) ? (ty * 4 + i) : (64 + ty * 4 + i - 4));
        float* po = H + (size_t)mm * DOUT + n0;
#pragma unroll
        for (int j = 0; j < 8; j++) {
            int nn = (j < 4) ? (tx * 4 + j) : (64 + tx * 4 + j - 4);
            float h = (float)(acc[i][j] + (double)bias[n0 + nn]);
            h = (h >= 0.0f) ? h : 0.01f * h;
            po[nn] = h;
        }
    }
}

// ---------------------------------------------------------------------------
// K2: brute-force EXACT sequential inhibition scan. 1 block x 256 threads.
// Reads H rows from ws, writes binary rows to out.
// phi_d = tbl[min(m-last_sel[d]-1,63)], tbl = exact f32 iterated
// min(p+GAMMA,1) (saturates to exactly 1.0 at index 62; initial phi=1 via
// the t=63 clamp with last_sel=-100000).
// Selection: exact top-10 by (s desc, idx asc) == lax.top_k order; binary=1
// and phi reset only where s>0 (zero/neg selections provably output-neutral).
// ---------------------------------------------------------------------------
__global__ __launch_bounds__(256)
void scan_kernel(const float* __restrict__ H, float* __restrict__ out) {
    __shared__ int   last_sel[DOUT];
    __shared__ float tbl[64];
    __shared__ u64   wave_top[4][10];
    __shared__ int   selid[16];
    __shared__ int   selcnt;
    const int tid  = threadIdx.x;
    const int lane = tid & 63;
    const int wv   = tid >> 6;

    for (int j = tid; j < DOUT; j += 256) last_sel[j] = -100000;
    if (tid == 0) {
        float p = 0.0f;
        tbl[0] = 0.0f;
        for (int i = 1; i < 64; i++) { p = fminf(p + GAMMA, 1.0f); tbl[i] = p; }
        selcnt = 0;
    }
    __syncthreads();

    // thread t covers columns c*1024 + t*4 .. +3 (coalesced float4)
    float4 cur[4];
#pragma unroll
    for (int c = 0; c < 4; c++)
        cur[c] = *(const float4*)(H + (size_t)(c * 1024 + tid * 4));

    for (int m = 0; m < NROWS; m++) {
        float4 nxt[4];
        if (m + 1 < NROWS) {
#pragma unroll
            for (int c = 0; c < 4; c++)
                nxt[c] = *(const float4*)(H + (size_t)(m + 1) * DOUT + c * 1024 + tid * 4);
        }

        // keys: (mono(s)<<32) | (0xFFFF - idx)  => max order = (s desc, idx asc)
        u64 k[16];
#pragma unroll
        for (int c = 0; c < 4; c++) {
#pragma unroll
            for (int q = 0; q < 4; q++) {
                int j = c * 1024 + tid * 4 + q;
                float h = ((const float*)&cur[c])[q];
                int ls = last_sel[j];
                int t = m - ls - 1; if (t > 63) t = 63;
                float s = h * tbl[t];
                k[c * 4 + q] = ((u64)mono_key(s) << 32) | (u32)(0xFFFFu - (u32)j);
            }
        }

        // per-wave top-10
#pragma unroll
        for (int r = 0; r < 10; r++) {
            u64 lm = 0;
#pragma unroll
            for (int i = 0; i < 16; i++) if (k[i] > lm) lm = k[i];
            u64 wm = wave_max64(lm);
#pragma unroll
            for (int i = 0; i < 16; i++) if (k[i] == wm) k[i] = 0;
            if (lane == 0) wave_top[wv][r] = wm;
        }
        __syncthreads();                                   // (A)

        if (wv == 0) {
            u64 mk = (lane < 40) ? wave_top[lane / 10][lane % 10] : 0;
            int cnt = 0;
            for (int r = 0; r < 10; r++) {
                u64 wm = wave_max64(mk);
                if (mk == wm) mk = 0;        // keys unique -> removes exactly one
                if (lane == 0) {
                    if ((u32)(wm >> 32) > 0x80000000u) {   // s > 0 strictly
                        int j = 0xFFFF - (int)(wm & 0xFFFFu);
                        selid[cnt++] = j;
                        last_sel[j] = m;
                    }
                }
            }
            if (lane == 0) selcnt = cnt;
        }
        __syncthreads();                                   // (B)

        float4 z = {0.0f, 0.0f, 0.0f, 0.0f};
#pragma unroll
        for (int c = 0; c < 4; c++)
            *(float4*)(out + (size_t)m * DOUT + c * 1024 + tid * 4) = z;
        __syncthreads();                                   // (C)
        if (tid < selcnt)
            out[(size_t)m * DOUT + selid[tid]] = 1.0f;

        if (m + 1 < NROWS) {
#pragma unroll
            for (int c = 0; c < 4; c++) cur[c] = nxt[c];
        }
        __syncthreads();                                   // (D)
    }
}

// ---------------------------------------------------------------------------
extern "C" void kernel_launch(void* const* d_in, const int* in_sizes, int n_in,
                              void* d_out, int out_size, void* d_ws, size_t ws_size,
                              hipStream_t stream) {
    const float* X  = (const float*)d_in[0];   // 8192 x 1024 f32 (beacon-verified)
    const float* Wt = (const float*)d_in[1];   // 4096 x 1024 f32
    const float* b  = (const float*)d_in[2];   // 4096 f32
    // d_in[3] = k == 10 (beacon-verified)
    float* out = (float*)d_out;
    float* H   = (float*)d_ws;                 // 128 MB, fits (beacon-verified)
    (void)in_sizes; (void)n_in; (void)out_size; (void)ws_size;

    gemm_lrelu_f64acc<<<dim3(32, 64), 256, 0, stream>>>(X, Wt, b, H);
    scan_kernel<<<dim3(1), 256, 0, stream>>>(H, out);
}

// Round 6
// 36941.809 us; speedup vs baseline: 2.6553x; 2.6553x over previous
//
#include <hip/hip_runtime.h>
#include <cstdint>
#include <cstddef>

typedef unsigned long long u64;
typedef unsigned int u32;

#define NROWS 8192
#define DIN   1024
#define DOUT  4096
#define GAMMA 0.01618f
#define NC    640                 // exact candidate depth: 620 max suppressed + 10 + margin
#define RQ    2048                // u64 stride between candidate rows (16 KB = one H row)

// monotone order-preserving fp32 -> u32 (ascending); s>0 <=> key > 0x80000000
__device__ __forceinline__ u32 mono_key(float f) {
    u32 u = __float_as_uint(f);
    return (u & 0x80000000u) ? ~u : (u | 0x80000000u);
}
__device__ __forceinline__ u32 unmono_key(u32 u) {
    return (u & 0x80000000u) ? (u ^ 0x80000000u) : ~u;
}

// 64-lane max of a u64 via two 32-bit shuffles per step (validated round 4/5)
__device__ __forceinline__ u64 wave_max64(u64 x) {
#pragma unroll
    for (int off = 32; off >= 1; off >>= 1) {
        u32 lo = (u32)x, hi = (u32)(x >> 32);
        u32 olo = __shfl_xor(lo, off, 64);
        u32 ohi = __shfl_xor(hi, off, 64);
        u64 o = ((u64)ohi << 32) | olo;
        if (o > x) x = o;
    }
    return x;
}

// ---------------------------------------------------------------------------
// K1 (validated round 5): H = leaky_relu(X @ W^T + b), f64 accumulation.
// ---------------------------------------------------------------------------
__global__ __launch_bounds__(256)
void gemm_lrelu_f64acc(const float* __restrict__ X, const float* __restrict__ Wt,
                       const float* __restrict__ bias, float* __restrict__ H) {
    __shared__ float As[16][128];
    __shared__ float Bs[16][128];
    const int bx = blockIdx.x;
    const int by = blockIdx.y;
    const int tid = threadIdx.x;
    const int tx = tid & 15, ty = tid >> 4;
    const int m0 = by * 128, n0 = bx * 128;

    double acc[8][8];
#pragma unroll
    for (int i = 0; i < 8; i++)
#pragma unroll
        for (int j = 0; j < 8; j++) acc[i][j] = 0.0;

    for (int k0 = 0; k0 < DIN; k0 += 16) {
#pragma unroll
        for (int h = 0; h < 2; h++) {
            int id = tid + h * 256;
            int r  = id >> 2;
            int kc = id & 3;
            float4 a = *(const float4*)(X  + (size_t)(m0 + r) * DIN + k0 + kc * 4);
            As[kc * 4 + 0][r] = a.x; As[kc * 4 + 1][r] = a.y;
            As[kc * 4 + 2][r] = a.z; As[kc * 4 + 3][r] = a.w;
            float4 b = *(const float4*)(Wt + (size_t)(n0 + r) * DIN + k0 + kc * 4);
            Bs[kc * 4 + 0][r] = b.x; Bs[kc * 4 + 1][r] = b.y;
            Bs[kc * 4 + 2][r] = b.z; Bs[kc * 4 + 3][r] = b.w;
        }
        __syncthreads();
#pragma unroll
        for (int kk = 0; kk < 16; kk++) {
            float a[8], b[8];
            *(float4*)&a[0] = *(const float4*)&As[kk][ty * 4];
            *(float4*)&a[4] = *(const float4*)&As[kk][64 + ty * 4];
            *(float4*)&b[0] = *(const float4*)&Bs[kk][tx * 4];
            *(float4*)&b[4] = *(const float4*)&Bs[kk][64 + tx * 4];
#pragma unroll
            for (int i = 0; i < 8; i++)
#pragma unroll
                for (int j = 0; j < 8; j++)
                    acc[i][j] += (double)a[i] * (double)b[j];
        }
        __syncthreads();
    }

#pragma unroll
    for (int i = 0; i < 8; i++) {
        int mm = m0 + ((i < 4) ? (ty * 4 + i) : (64 + ty * 4 + i - 4));
        float* po = H + (size_t)mm * DOUT + n0;
#pragma unroll
        for (int j = 0; j < 8; j++) {
            int nn = (j < 4) ? (tx * 4 + j) : (64 + tx * 4 + j - 4);
            float h = (float)(acc[i][j] + (double)bias[n0 + nn]);
            h = (h >= 0.0f) ? h : 0.01f * h;
            po[nn] = h;
        }
    }
}

// ---------------------------------------------------------------------------
// K2: per-row exact top-640 by (h desc, idx asc). Full bitonic-4096 descending
// sort of packed keys in LDS, then the first 640 keys are written IN PLACE
// over the row's own start (u64[640] = first 5120 B of the 16 KB row).
// ---------------------------------------------------------------------------
__global__ __launch_bounds__(256)
void topk640_kernel(float* __restrict__ H) {
    __shared__ u64 skey[DOUT];     // 32 KB
    const int row = blockIdx.x;
    const int tid = threadIdx.x;
    float* hrow = H + (size_t)row * DOUT;

#pragma unroll
    for (int c = 0; c < 4; c++) {
        int j = c * 1024 + tid * 4;
        float4 v = *(const float4*)(hrow + j);
        skey[j + 0] = ((u64)mono_key(v.x) << 32) | (u32)(0xFFFFu - (u32)(j + 0));
        skey[j + 1] = ((u64)mono_key(v.y) << 32) | (u32)(0xFFFFu - (u32)(j + 1));
        skey[j + 2] = ((u64)mono_key(v.z) << 32) | (u32)(0xFFFFu - (u32)(j + 2));
        skey[j + 3] = ((u64)mono_key(v.w) << 32) | (u32)(0xFFFFu - (u32)(j + 3));
    }
    // bitonic sort 4096, descending (verified by hand on size-4 case)
    for (int size = 2; size <= DOUT; size <<= 1)
        for (int stride = size >> 1; stride > 0; stride >>= 1) {
            __syncthreads();
#pragma unroll 2
            for (int i = tid; i < DOUT / 2; i += 256) {
                int pos = 2 * i - (i & (stride - 1));
                u64 a = skey[pos], b = skey[pos + stride];
                bool up = (pos & size) == 0;
                if ((a < b) == up) { skey[pos] = b; skey[pos + stride] = a; }
            }
        }
    __syncthreads();
    u64* cand = (u64*)hrow;
    for (int j = tid; j < NC; j += 256) cand[j] = skey[j];
}

// ---------------------------------------------------------------------------
// K3: sequential inhibition scan over candidates. 1 block x 64 lanes.
// Per row: chunk of 64 sorted candidates; compute s = h * phi; extract top-10
// via 10 x wave_max64 (validated machinery) with re-injection of the running
// top-10 when more chunks are needed. Stop when theta=(10th s) > 0 and
// theta > next candidate's h (strict) -> remaining candidates/columns can't
// enter the s>0 part of the top-10 (exact; see round-5 analysis).
// Winners with s>0: out=1, last_sel=m. Single wave -> one barrier per row.
// ---------------------------------------------------------------------------
__global__ __launch_bounds__(64)
void scan_kernel(const u64* __restrict__ cand, float* __restrict__ out) {
    __shared__ int   last_sel[DOUT];   // 16 KB
    __shared__ float tbl[64];
    const int lane = threadIdx.x;

    for (int j = lane; j < DOUT; j += 64) last_sel[j] = -100000;
    if (lane == 0) {
        float p = 0.0f;
        tbl[0] = 0.0f;
        for (int i = 1; i < 64; i++) { p = fminf(p + GAMMA, 1.0f); tbl[i] = p; }
    }
    __syncthreads();

    u64 pre = cand[lane];              // row 0, chunk 0 (coalesced 512 B)

    for (int m = 0; m < NROWS; m++) {
        const u64* crow = cand + (size_t)m * RQ;
        u64 nxt = 0;
        if (m + 1 < NROWS) nxt = cand[(size_t)(m + 1) * RQ + lane];  // prefetch

        u64 tt[10];
#pragma unroll 1
        for (int it = 0; it < 10; it++) {
            u64 ck = (it == 0) ? pre : crow[it * 64 + lane];
            u32 hbits = unmono_key((u32)(ck >> 32));
            int id = 0xFFFF - (int)(ck & 0xFFFFu);
            int t = m - last_sel[id] - 1; if (t > 63) t = 63;
            float s = __uint_as_float(hbits) * tbl[t];
            u64 key = ((u64)mono_key(s) << 32) | (ck & 0xFFFFu);
            u64 key2 = 0;
            if (it > 0) {              // re-inject running top-10 on lanes 0..9
#pragma unroll
                for (int rr = 0; rr < 10; rr++) if (lane == rr) key2 = tt[rr];
            }
#pragma unroll
            for (int rr = 0; rr < 10; rr++) {
                u64 mx = (key > key2) ? key : key2;
                u64 wm = wave_max64(mx);
                if (key == wm)  key = 0;    // unique keys -> exactly one removal
                if (key2 == wm) key2 = 0;
                tt[rr] = wm;
            }
            if (it == 9) break;
            u32 thr = (u32)(tt[9] >> 32);
            u32 headhi = (u32)(crow[(it + 1) * 64] >> 32);   // broadcast load
            if (thr > 0x80000000u && thr > headhi) break;     // exact stop
        }

        // lanes 0..9 apply winners (distinct idx guaranteed)
        u64 wk = 0;
#pragma unroll
        for (int rr = 0; rr < 10; rr++) if (lane == rr) wk = tt[rr];
        if (lane < 10 && (u32)(wk >> 32) > 0x80000000u) {     // s > 0 strictly
            int j = 0xFFFF - (int)(wk & 0xFFFFu);
            out[(size_t)m * DOUT + j] = 1.0f;
            last_sel[j] = m;
        }
        pre = nxt;
        __syncthreads();   // order last_sel writes before next row's reads
    }
}

// ---------------------------------------------------------------------------
extern "C" void kernel_launch(void* const* d_in, const int* in_sizes, int n_in,
                              void* d_out, int out_size, void* d_ws, size_t ws_size,
                              hipStream_t stream) {
    const float* X  = (const float*)d_in[0];   // 8192 x 1024 f32
    const float* Wt = (const float*)d_in[1];   // 4096 x 1024 f32
    const float* b  = (const float*)d_in[2];   // 4096 f32
    // d_in[3] = k == 10 (beacon-verified)
    float* out = (float*)d_out;
    float* H   = (float*)d_ws;                 // 128 MB (beacon-verified)
    (void)in_sizes; (void)n_in; (void)out_size; (void)ws_size;

    // K1: GEMM + leaky -> H (ws)
    gemm_lrelu_f64acc<<<dim3(32, 64), 256, 0, stream>>>(X, Wt, b, H);
    // K2: per-row exact sorted top-640, written in place over each row's start
    topk640_kernel<<<dim3(NROWS), 256, 0, stream>>>(H);
    // zero the binary output (harness poisons it with 0xAA)
    hipMemsetAsync(d_out, 0, (size_t)NROWS * DOUT * sizeof(float), stream);
    // K3: sequential scan over candidates
    scan_kernel<<<dim3(1), 64, 0, stream>>>((const u64*)H, out);
}

// Round 7
// 9573.257 us; speedup vs baseline: 10.2465x; 3.8589x over previous
//
#include <hip/hip_runtime.h>
#include <cstdint>
#include <cstddef>

typedef unsigned long long u64;
typedef unsigned int u32;

#define NROWS 8192
#define DIN   1024
#define DOUT  4096
#define GAMMA 0.01618f
#define NC    640                 // exact candidate depth: 620 max suppressed + 10 + margin
#define RQ    2048                // u64 stride between candidate rows (16 KB = one H row)

// monotone order-preserving fp32 -> u32 (ascending); s>0 <=> key > 0x80000000
__device__ __forceinline__ u32 mono_key(float f) {
    u32 u = __float_as_uint(f);
    return (u & 0x80000000u) ? ~u : (u | 0x80000000u);
}
__device__ __forceinline__ u32 unmono_key(u32 u) {
    return (u & 0x80000000u) ? (u ^ 0x80000000u) : ~u;
}

// 64-lane max of a u64 via two 32-bit shuffles per step (validated r4-r6)
__device__ __forceinline__ u64 wave_max64(u64 x) {
#pragma unroll
    for (int off = 32; off >= 1; off >>= 1) {
        u32 lo = (u32)x, hi = (u32)(x >> 32);
        u32 olo = __shfl_xor(lo, off, 64);
        u32 ohi = __shfl_xor(hi, off, 64);
        u64 o = ((u64)ohi << 32) | olo;
        if (o > x) x = o;
    }
    return x;
}
__device__ __forceinline__ u64 shfl_u64(u64 x, int src) {
    u32 lo = __shfl((u32)x, src, 64);
    u32 hi = __shfl((u32)(x >> 32), src, 64);
    return ((u64)hi << 32) | lo;
}

// ---------------------------------------------------------------------------
// K1 (validated r5/r6): H = leaky_relu(X @ W^T + b), f64 accumulation.
// ---------------------------------------------------------------------------
__global__ __launch_bounds__(256)
void gemm_lrelu_f64acc(const float* __restrict__ X, const float* __restrict__ Wt,
                       const float* __restrict__ bias, float* __restrict__ H) {
    __shared__ float As[16][128];
    __shared__ float Bs[16][128];
    const int bx = blockIdx.x;
    const int by = blockIdx.y;
    const int tid = threadIdx.x;
    const int tx = tid & 15, ty = tid >> 4;
    const int m0 = by * 128, n0 = bx * 128;

    double acc[8][8];
#pragma unroll
    for (int i = 0; i < 8; i++)
#pragma unroll
        for (int j = 0; j < 8; j++) acc[i][j] = 0.0;

    for (int k0 = 0; k0 < DIN; k0 += 16) {
#pragma unroll
        for (int h = 0; h < 2; h++) {
            int id = tid + h * 256;
            int r  = id >> 2;
            int kc = id & 3;
            float4 a = *(const float4*)(X  + (size_t)(m0 + r) * DIN + k0 + kc * 4);
            As[kc * 4 + 0][r] = a.x; As[kc * 4 + 1][r] = a.y;
            As[kc * 4 + 2][r] = a.z; As[kc * 4 + 3][r] = a.w;
            float4 b = *(const float4*)(Wt + (size_t)(n0 + r) * DIN + k0 + kc * 4);
            Bs[kc * 4 + 0][r] = b.x; Bs[kc * 4 + 1][r] = b.y;
            Bs[kc * 4 + 2][r] = b.z; Bs[kc * 4 + 3][r] = b.w;
        }
        __syncthreads();
#pragma unroll
        for (int kk = 0; kk < 16; kk++) {
            float a[8], b[8];
            *(float4*)&a[0] = *(const float4*)&As[kk][ty * 4];
            *(float4*)&a[4] = *(const float4*)&As[kk][64 + ty * 4];
            *(float4*)&b[0] = *(const float4*)&Bs[kk][tx * 4];
            *(float4*)&b[4] = *(const float4*)&Bs[kk][64 + tx * 4];
#pragma unroll
            for (int i = 0; i < 8; i++)
#pragma unroll
                for (int j = 0; j < 8; j++)
                    acc[i][j] += (double)a[i] * (double)b[j];
        }
        __syncthreads();
    }

#pragma unroll
    for (int i = 0; i < 8; i++) {
        int mm = m0 + ((i < 4) ? (ty * 4 + i) : (64 + ty * 4 + i - 4));
        float* po = H + (size_t)mm * DOUT + n0;
#pragma unroll
        for (int j = 0; j < 8; j++) {
            int nn = (j < 4) ? (tx * 4 + j) : (64 + tx * 4 + j - 4);
            float h = (float)(acc[i][j] + (double)bias[n0 + nn]);
            h = (h >= 0.0f) ? h : 0.01f * h;
            po[nn] = h;
        }
    }
}

// ---------------------------------------------------------------------------
// K2 (validated r6): per-row exact top-640 by (h desc, idx asc); bitonic-4096
// desc in LDS; first 640 mono-form keys written in place over the row start.
// ---------------------------------------------------------------------------
__global__ __launch_bounds__(256)
void topk640_kernel(float* __restrict__ H) {
    __shared__ u64 skey[DOUT];     // 32 KB
    const int row = blockIdx.x;
    const int tid = threadIdx.x;
    float* hrow = H + (size_t)row * DOUT;

#pragma unroll
    for (int c = 0; c < 4; c++) {
        int j = c * 1024 + tid * 4;
        float4 v = *(const float4*)(hrow + j);
        skey[j + 0] = ((u64)mono_key(v.x) << 32) | (u32)(0xFFFFu - (u32)(j + 0));
        skey[j + 1] = ((u64)mono_key(v.y) << 32) | (u32)(0xFFFFu - (u32)(j + 1));
        skey[j + 2] = ((u64)mono_key(v.z) << 32) | (u32)(0xFFFFu - (u32)(j + 2));
        skey[j + 3] = ((u64)mono_key(v.w) << 32) | (u32)(0xFFFFu - (u32)(j + 3));
    }
    for (int size = 2; size <= DOUT; size <<= 1)
        for (int stride = size >> 1; stride > 0; stride >>= 1) {
            __syncthreads();
#pragma unroll 2
            for (int i = tid; i < DOUT / 2; i += 256) {
                int pos = 2 * i - (i & (stride - 1));
                u64 a = skey[pos], b = skey[pos + stride];
                bool up = (pos & size) == 0;
                if ((a < b) == up) { skey[pos] = b; skey[pos + stride] = a; }
            }
        }
    __syncthreads();
    u64* cand = (u64*)hrow;
    for (int j = tid; j < NC; j += 256) cand[j] = skey[j];
}

// ---------------------------------------------------------------------------
// K3: sequential scan, 1 block x 1 wave (64 lanes), NO barriers.
// Fast path (expected ~85-95% of rows): suppressed set uncorrelated with this
// row's h-ranking (rows iid) -> top-10 of s = first 10 unsuppressed candidates
// in sorted order, validated by 3 exact conditions:
//   nu>=10, no suppressed key beats the 10th unsuppressed key,
//   key10 > key64 (full 64-bit; all outside-chunk s-keys are < key64:
//   unsup outside keys are < key64 by sortedness; suppressed outside have
//   s <= 0.987h < h64 for h>0 and s<=0 otherwise) and s10 > 0.
// Fallback: r6-validated iterative 10 x wave_max64 with re-injection + exact
// early stop. phi via lane-distributed table (__shfl), chunk0+key64 prefetched
// one row ahead -> no global load in the dependent chain.
// ---------------------------------------------------------------------------
__global__ __launch_bounds__(64)
void scan_kernel(const u64* __restrict__ cand, float* __restrict__ out) {
    __shared__ int last_sel[DOUT];   // 16 KB
    const int lane = threadIdx.x;

    for (int j = lane; j < DOUT; j += 64) last_sel[j] = -100000;

    // lane i holds tbl[i]: tbl[0]=0, tbl[i]=min(tbl[i-1]+GAMMA,1) (exact fp32,
    // saturates to exactly 1.0 at i=62; i=63 covers "fully recovered")
    float tbl_r = 0.0f;
    {
        float p = 0.0f;
        for (int i = 0; i < 64; i++) {
            if (i == lane) tbl_r = p;
            p = fminf(p + GAMMA, 1.0f);
        }
    }
    const u64 lmask_lt = (lane == 0) ? 0ull : ((1ull << lane) - 1ull);

    u64 preA  = cand[lane];      // row 0 chunk 0 (per-lane)
    u64 pre64 = cand[64];        // row 0 candidate 64 (uniform broadcast)

    for (int m = 0; m < NROWS; m++) {
        const u64 c   = preA;
        const u64 k64 = pre64;
        // prefetch next row immediately (hidden under this row's chain)
        {
            int mp = (m + 1 < NROWS) ? m + 1 : m;
            preA  = cand[(size_t)mp * RQ + lane];
            pre64 = cand[(size_t)mp * RQ + 64];
        }

        const int id = 0xFFFF - (int)(c & 0xFFFFu);
        int t = m - last_sel[id] - 1; if (t > 63) t = 63;
        const float phi = __shfl(tbl_r, t);
        const bool unsup = (phi == 1.0f);
        const float v = __uint_as_float(unmono_key((u32)(c >> 32)));
        const float s = v * phi;
        // for unsup lanes s==v exactly -> skey==c (sorted order preserved)
        const u64 skey = ((u64)mono_key(s) << 32) | (c & 0xFFFFu);

        const u64 mu = __ballot(unsup);
        const int nu = __popcll(mu);
        bool fast = false;
        u64 key10 = 0;
        if (nu >= 10) {
            u64 um = mu;
#pragma unroll
            for (int q = 0; q < 9; q++) um &= um - 1;      // clear 9 lowest
            const int lane10 = __ffsll((long long)um) - 1; // 10th unsup lane
            key10 = shfl_u64(skey, lane10);
            const bool beat = (!unsup) && (skey > key10);
            const u64 anybeat = __ballot(beat);
            fast = (anybeat == 0ull) && (key10 > k64) &&
                   ((u32)(key10 >> 32) > 0x80000000u);     // s10 > 0 strictly
        }

        if (fast) {
            const int prefix = __popcll(mu & lmask_lt);
            if (unsup && prefix < 10) {                    // s >= s10 > 0
                out[(size_t)m * DOUT + id] = 1.0f;
                last_sel[id] = m;
            }
        } else {
            // ---- r6-validated fallback ----
            const u64* crow = cand + (size_t)m * RQ;
            u64 tt[10];
            u64 key = skey, key2 = 0;
#pragma unroll 1
            for (int it = 0; it < 10; it++) {
                if (it > 0) {
                    u64 ck = crow[it * 64 + lane];
                    u32 hbits = unmono_key((u32)(ck >> 32));
                    int id2 = 0xFFFF - (int)(ck & 0xFFFFu);
                    int t2 = m - last_sel[id2] - 1; if (t2 > 63) t2 = 63;
                    float s2 = __uint_as_float(hbits) * __shfl(tbl_r, t2);
                    key = ((u64)mono_key(s2) << 32) | (ck & 0xFFFFu);
                    key2 = 0;
#pragma unroll
                    for (int rr = 0; rr < 10; rr++) if (lane == rr) key2 = tt[rr];
                }
#pragma unroll
                for (int rr = 0; rr < 10; rr++) {
                    u64 mx = (key > key2) ? key : key2;
                    u64 wm = wave_max64(mx);
                    if (key == wm)  key = 0;
                    if (key2 == wm) key2 = 0;
                    tt[rr] = wm;
                }
                if (it == 9) break;
                u32 thr = (u32)(tt[9] >> 32);
                u32 headhi = (u32)(crow[(it + 1) * 64] >> 32);
                if (thr > 0x80000000u && thr > headhi) break;
            }
            u64 wk = 0;
#pragma unroll
            for (int rr = 0; rr < 10; rr++) if (lane == rr) wk = tt[rr];
            if (lane < 10 && (u32)(wk >> 32) > 0x80000000u) {
                int j = 0xFFFF - (int)(wk & 0xFFFFu);
                out[(size_t)m * DOUT + j] = 1.0f;
                last_sel[j] = m;
            }
        }
        // single wave: LDS writes ordered before next iteration's reads by
        // program order + compiler lgkmcnt; no barrier needed.
    }
}

// ---------------------------------------------------------------------------
extern "C" void kernel_launch(void* const* d_in, const int* in_sizes, int n_in,
                              void* d_out, int out_size, void* d_ws, size_t ws_size,
                              hipStream_t stream) {
    const float* X  = (const float*)d_in[0];   // 8192 x 1024 f32
    const float* Wt = (const float*)d_in[1];   // 4096 x 1024 f32
    const float* b  = (const float*)d_in[2];   // 4096 f32
    // d_in[3] = k == 10 (beacon-verified)
    float* out = (float*)d_out;
    float* H   = (float*)d_ws;                 // 128 MB (beacon-verified)
    (void)in_sizes; (void)n_in; (void)out_size; (void)ws_size;

    gemm_lrelu_f64acc<<<dim3(32, 64), 256, 0, stream>>>(X, Wt, b, H);
    topk640_kernel<<<dim3(NROWS), 256, 0, stream>>>(H);
    hipMemsetAsync(d_out, 0, (size_t)NROWS * DOUT * sizeof(float), stream);
    scan_kernel<<<dim3(1), 64, 0, stream>>>((const u64*)H, out);
}

// Round 8
// 7802.669 us; speedup vs baseline: 12.5716x; 1.2269x over previous
//
#include <hip/hip_runtime.h>
#include <cstdint>
#include <cstddef>

typedef unsigned long long u64;
typedef unsigned int u32;

#define NROWS 8192
#define DIN   1024
#define DOUT  4096
#define GAMMA 0.01618f
#define NC    640                 // exact candidate depth: 620 max suppressed + 10 + margin
#define RQ    2048                // u64 stride between candidate rows (16 KB = one H row)

// monotone order-preserving fp32 -> u32 (ascending); s>0 <=> key > 0x80000000
__device__ __forceinline__ u32 mono_key(float f) {
    u32 u = __float_as_uint(f);
    return (u & 0x80000000u) ? ~u : (u | 0x80000000u);
}
__device__ __forceinline__ u32 unmono_key(u32 u) {
    return (u & 0x80000000u) ? (u ^ 0x80000000u) : ~u;
}

// 64-lane max of a u64 via two 32-bit shuffles per step (validated r4-r7)
__device__ __forceinline__ u64 wave_max64(u64 x) {
#pragma unroll
    for (int off = 32; off >= 1; off >>= 1) {
        u32 lo = (u32)x, hi = (u32)(x >> 32);
        u32 olo = __shfl_xor(lo, off, 64);
        u32 ohi = __shfl_xor(hi, off, 64);
        u64 o = ((u64)ohi << 32) | olo;
        if (o > x) x = o;
    }
    return x;
}
__device__ __forceinline__ u64 wave_min64(u64 x) {
#pragma unroll
    for (int off = 32; off >= 1; off >>= 1) {
        u32 lo = (u32)x, hi = (u32)(x >> 32);
        u32 olo = __shfl_xor(lo, off, 64);
        u32 ohi = __shfl_xor(hi, off, 64);
        u64 o = ((u64)ohi << 32) | olo;
        if (o < x) x = o;
    }
    return x;
}
__device__ __forceinline__ u64 shfl_u64(u64 x, int src) {
    u32 lo = __shfl((u32)x, src, 64);
    u32 hi = __shfl((u32)(x >> 32), src, 64);
    return ((u64)hi << 32) | lo;
}

// ---------------------------------------------------------------------------
// K1 (validated r5-r7): H = leaky_relu(X @ W^T + b), f64 accumulation.
// ---------------------------------------------------------------------------
__global__ __launch_bounds__(256)
void gemm_lrelu_f64acc(const float* __restrict__ X, const float* __restrict__ Wt,
                       const float* __restrict__ bias, float* __restrict__ H) {
    __shared__ float As[16][128];
    __shared__ float Bs[16][128];
    const int bx = blockIdx.x;
    const int by = blockIdx.y;
    const int tid = threadIdx.x;
    const int tx = tid & 15, ty = tid >> 4;
    const int m0 = by * 128, n0 = bx * 128;

    double acc[8][8];
#pragma unroll
    for (int i = 0; i < 8; i++)
#pragma unroll
        for (int j = 0; j < 8; j++) acc[i][j] = 0.0;

    for (int k0 = 0; k0 < DIN; k0 += 16) {
#pragma unroll
        for (int h = 0; h < 2; h++) {
            int id = tid + h * 256;
            int r  = id >> 2;
            int kc = id & 3;
            float4 a = *(const float4*)(X  + (size_t)(m0 + r) * DIN + k0 + kc * 4);
            As[kc * 4 + 0][r] = a.x; As[kc * 4 + 1][r] = a.y;
            As[kc * 4 + 2][r] = a.z; As[kc * 4 + 3][r] = a.w;
            float4 b = *(const float4*)(Wt + (size_t)(n0 + r) * DIN + k0 + kc * 4);
            Bs[kc * 4 + 0][r] = b.x; Bs[kc * 4 + 1][r] = b.y;
            Bs[kc * 4 + 2][r] = b.z; Bs[kc * 4 + 3][r] = b.w;
        }
        __syncthreads();
#pragma unroll
        for (int kk = 0; kk < 16; kk++) {
            float a[8], b[8];
            *(float4*)&a[0] = *(const float4*)&As[kk][ty * 4];
            *(float4*)&a[4] = *(const float4*)&As[kk][64 + ty * 4];
            *(float4*)&b[0] = *(const float4*)&Bs[kk][tx * 4];
            *(float4*)&b[4] = *(const float4*)&Bs[kk][64 + tx * 4];
#pragma unroll
            for (int i = 0; i < 8; i++)
#pragma unroll
                for (int j = 0; j < 8; j++)
                    acc[i][j] += (double)a[i] * (double)b[j];
        }
        __syncthreads();
    }

#pragma unroll
    for (int i = 0; i < 8; i++) {
        int mm = m0 + ((i < 4) ? (ty * 4 + i) : (64 + ty * 4 + i - 4));
        float* po = H + (size_t)mm * DOUT + n0;
#pragma unroll
        for (int j = 0; j < 8; j++) {
            int nn = (j < 4) ? (tx * 4 + j) : (64 + tx * 4 + j - 4);
            float h = (float)(acc[i][j] + (double)bias[n0 + nn]);
            h = (h >= 0.0f) ? h : 0.01f * h;
            po[nn] = h;
        }
    }
}

// ---------------------------------------------------------------------------
// K2 (validated r6/r7): per-row exact top-640 by (h desc, idx asc); bitonic-
// 4096 desc in LDS; first 640 mono-form keys written in place over row start.
// ---------------------------------------------------------------------------
__global__ __launch_bounds__(256)
void topk640_kernel(float* __restrict__ H) {
    __shared__ u64 skey[DOUT];     // 32 KB
    const int row = blockIdx.x;
    const int tid = threadIdx.x;
    float* hrow = H + (size_t)row * DOUT;

#pragma unroll
    for (int c = 0; c < 4; c++) {
        int j = c * 1024 + tid * 4;
        float4 v = *(const float4*)(hrow + j);
        skey[j + 0] = ((u64)mono_key(v.x) << 32) | (u32)(0xFFFFu - (u32)(j + 0));
        skey[j + 1] = ((u64)mono_key(v.y) << 32) | (u32)(0xFFFFu - (u32)(j + 1));
        skey[j + 2] = ((u64)mono_key(v.z) << 32) | (u32)(0xFFFFu - (u32)(j + 2));
        skey[j + 3] = ((u64)mono_key(v.w) << 32) | (u32)(0xFFFFu - (u32)(j + 3));
    }
    for (int size = 2; size <= DOUT; size <<= 1)
        for (int stride = size >> 1; stride > 0; stride >>= 1) {
            __syncthreads();
#pragma unroll 2
            for (int i = tid; i < DOUT / 2; i += 256) {
                int pos = 2 * i - (i & (stride - 1));
                u64 a = skey[pos], b = skey[pos + stride];
                bool up = (pos & size) == 0;
                if ((a < b) == up) { skey[pos] = b; skey[pos + stride] = a; }
            }
        }
    __syncthreads();
    u64* cand = (u64*)hrow;
    for (int j = tid; j < NC; j += 256) cand[j] = skey[j];
}

// ---------------------------------------------------------------------------
// K3: sequential scan, 1 block x 1 wave, no barriers.
// In-chunk exact top-10 with beater-merge (see round-7 analysis):
//   true in-chunk top-10 subset of {first 10 unsup} U {beaters(key>key10)};
//   beater ranks via readlane+ballot; unsup ranks = prefix + #beaters above;
//   theta = min winner key; valid iff theta.s > 0 and theta > key(cand 64)
//   (covers every outside-chunk candidate exactly).
// Fallback (r6-validated, exact): iterative 10 x wave_max64 over 640 cands.
// ---------------------------------------------------------------------------
__global__ __launch_bounds__(64)
void scan_kernel(const u64* __restrict__ cand, float* __restrict__ out) {
    __shared__ int last_sel[DOUT];   // 16 KB
    const int lane = threadIdx.x;

    for (int j = lane; j < DOUT; j += 64) last_sel[j] = -100000;

    // lane i holds tbl[i]: tbl[0]=0, tbl[i]=min(tbl[i-1]+GAMMA,1) (exact fp32,
    // saturates to exactly 1.0 at i=62)
    float tbl_r = 0.0f;
    {
        float p = 0.0f;
        for (int i = 0; i < 64; i++) {
            if (i == lane) tbl_r = p;
            p = fminf(p + GAMMA, 1.0f);
        }
    }
    const u64 lmask_lt = (lane == 0) ? 0ull : ((1ull << lane) - 1ull);

    u64 preA  = cand[lane];      // row 0 chunk 0 (per-lane)
    u64 pre64 = cand[64];        // row 0 candidate 64 (uniform)

    for (int m = 0; m < NROWS; m++) {
        const u64 c   = preA;
        const u64 k64 = pre64;
        {
            int mp = (m + 1 < NROWS) ? m + 1 : m;
            preA  = cand[(size_t)mp * RQ + lane];
            pre64 = cand[(size_t)mp * RQ + 64];
        }

        const int id = 0xFFFF - (int)(c & 0xFFFFu);
        int t = m - last_sel[id] - 1; if (t > 63) t = 63;
        const float phi = __shfl(tbl_r, t);
        const bool unsup = (phi == 1.0f);
        const float v = __uint_as_float(unmono_key((u32)(c >> 32)));
        const float s = v * phi;
        // unsup: s==v exactly -> skey==c (sorted order preserved)
        const u64 skey = ((u64)mono_key(s) << 32) | (c & 0xFFFFu);

        const u64 mu = __ballot(unsup);
        const int nu = __popcll(mu);
        const int prefix = __popcll(mu & lmask_lt);

        bool resolved = false, win = false;
        if (nu >= 10) {
            u64 um = mu;
#pragma unroll
            for (int q = 0; q < 9; q++) um &= um - 1;      // clear 9 lowest
            const int lane10 = __ffsll((long long)um) - 1; // 10th unsup lane
            const u64 key10 = shfl_u64(skey, lane10);
            const u64 beat = __ballot(skey > key10) & ~mu; // sup beaters only
            u64 theta;
            if (beat == 0ull) {
                win = unsup && (prefix < 10);
                theta = key10;
            } else {
                // merge: winners from {first 10 unsup} U beaters, exact ranks
                int myExtra = 0;        // #beaters with key > my skey
                int myrank  = 64;       // full in-chunk rank (beater lanes)
                u64 bm = beat;
                while (bm) {
                    const int l = __ffsll((long long)bm) - 1;
                    bm &= bm - 1;
                    const u64 kb = shfl_u64(skey, l);
                    const u64 g = __ballot(skey > kb);   // only unsup/beaters can be >
                    if (lane == l) myrank = __popcll(g);
                    myExtra += (kb > skey) ? 1 : 0;
                }
                const bool isbeat = (beat >> lane) & 1ull;
                win = unsup ? (prefix + myExtra < 10) : (isbeat && myrank < 10);
                theta = wave_min64(win ? skey : ~0ull);  // 10th best overall
            }
            resolved = ((u32)(theta >> 32) > 0x80000000u) && (theta > k64);
        }

        if (resolved) {
            if (win) {                                   // s >= theta > 0
                out[(size_t)m * DOUT + id] = 1.0f;
                last_sel[id] = m;
            }
        } else {
            // ---- r6-validated exact fallback over up to 640 candidates ----
            const u64* crow = cand + (size_t)m * RQ;
            u64 tt[10];
            u64 key = skey, key2 = 0;
#pragma unroll 1
            for (int it = 0; it < 10; it++) {
                if (it > 0) {
                    u64 ck = crow[it * 64 + lane];
                    u32 hbits = unmono_key((u32)(ck >> 32));
                    int id2 = 0xFFFF - (int)(ck & 0xFFFFu);
                    int t2 = m - last_sel[id2] - 1; if (t2 > 63) t2 = 63;
                    float s2 = __uint_as_float(hbits) * __shfl(tbl_r, t2);
                    key = ((u64)mono_key(s2) << 32) | (ck & 0xFFFFu);
                    key2 = 0;
#pragma unroll
                    for (int rr = 0; rr < 10; rr++) if (lane == rr) key2 = tt[rr];
                }
#pragma unroll
                for (int rr = 0; rr < 10; rr++) {
                    u64 mx = (key > key2) ? key : key2;
                    u64 wm = wave_max64(mx);
                    if (key == wm)  key = 0;
                    if (key2 == wm) key2 = 0;
                    tt[rr] = wm;
                }
                if (it == 9) break;
                u32 thr = (u32)(tt[9] >> 32);
                u32 headhi = (u32)(crow[(it + 1) * 64] >> 32);
                if (thr > 0x80000000u && thr > headhi) break;
            }
            u64 wk = 0;
#pragma unroll
            for (int rr = 0; rr < 10; rr++) if (lane == rr) wk = tt[rr];
            if (lane < 10 && (u32)(wk >> 32) > 0x80000000u) {
                int j = 0xFFFF - (int)(wk & 0xFFFFu);
                out[(size_t)m * DOUT + j] = 1.0f;
                last_sel[j] = m;
            }
        }
        // single wave: LDS writes ordered before next iteration's reads by
        // program order; no barrier needed.
    }
}

// ---------------------------------------------------------------------------
extern "C" void kernel_launch(void* const* d_in, const int* in_sizes, int n_in,
                              void* d_out, int out_size, void* d_ws, size_t ws_size,
                              hipStream_t stream) {
    const float* X  = (const float*)d_in[0];   // 8192 x 1024 f32
    const float* Wt = (const float*)d_in[1];   // 4096 x 1024 f32
    const float* b  = (const float*)d_in[2];   // 4096 f32
    // d_in[3] = k == 10 (beacon-verified)
    float* out = (float*)d_out;
    float* H   = (float*)d_ws;                 // 128 MB (beacon-verified)
    (void)in_sizes; (void)n_in; (void)out_size; (void)ws_size;

    gemm_lrelu_f64acc<<<dim3(32, 64), 256, 0, stream>>>(X, Wt, b, H);
    topk640_kernel<<<dim3(NROWS), 256, 0, stream>>>(H);
    hipMemsetAsync(d_out, 0, (size_t)NROWS * DOUT * sizeof(float), stream);
    scan_kernel<<<dim3(1), 64, 0, stream>>>((const u64*)H, out);
}